// Round 1
// baseline (399.742 us; speedup 1.0000x reference)
//
#include <hip/hip_runtime.h>
#include <stdint.h>

#define NR 8192
#define DE 1024
#define DC 512
#define NCH 16          // column chunks (8192/512)
#define BIGF 9999999.0f
#define MARG 0.3f

typedef __attribute__((ext_vector_type(8))) short bf16x8;
typedef __attribute__((ext_vector_type(4))) float f32x4;
typedef unsigned long long u64;

static __device__ __forceinline__ u64 umax64(u64 a, u64 b) { return a > b ? a : b; }
static __device__ __forceinline__ u64 umin64(u64 a, u64 b) { return a < b ? a : b; }

// merge sorted pair (p1>=p2) with sorted pair (o1>=o2) -> top2 of union
static __device__ __forceinline__ void merge_top2(u64& p1, u64& p2, u64 o1, u64 o2) {
    bool a = p1 >= o1;
    u64 hi = a ? p1 : o1;
    u64 lo = a ? o1 : p1;
    u64 s  = a ? p2 : o2;
    p1 = hi;
    p2 = umax64(lo, s);
}

static __device__ __forceinline__ unsigned short f2bf(float x) {
    unsigned u = __float_as_uint(x);
    unsigned r = u + 0x7FFFu + ((u >> 16) & 1u);
    return (unsigned short)(r >> 16);
}

// ---------------- K1: emb -> bf16, sq[i] = ||emb_i||^2 (fp32) ----------------
__global__ __launch_bounds__(256) void k_prep_emb(const float* __restrict__ emb,
                                                  short* __restrict__ embb,
                                                  float* __restrict__ sq) {
    int row = blockIdx.x, tid = threadIdx.x;
    float4 v = ((const float4*)(emb + (size_t)row * DE))[tid];   // 1024/4 = 256 float4
    float s = v.x * v.x + v.y * v.y + v.z * v.z + v.w * v.w;
    ushort4 b;
    b.x = f2bf(v.x); b.y = f2bf(v.y); b.z = f2bf(v.z); b.w = f2bf(v.w);
    *(ushort4*)&embb[(size_t)row * DE + tid * 4] = b;
    for (int m = 1; m < 64; m <<= 1) s += __shfl_xor(s, m);
    __shared__ float red[4];
    if ((tid & 63) == 0) red[tid >> 6] = s;
    __syncthreads();
    if (tid == 0) sq[row] = red[0] + red[1] + red[2] + red[3];
}

// ---------------- K2: nrm[i] = ||clot_i|| ----------------
__global__ __launch_bounds__(128) void k_nrm(const float* __restrict__ clot,
                                             float* __restrict__ nrm) {
    int row = blockIdx.x, tid = threadIdx.x;
    float4 v = ((const float4*)(clot + (size_t)row * DC))[tid];  // 512/4 = 128 float4
    float s = v.x * v.x + v.y * v.y + v.z * v.z + v.w * v.w;
    for (int m = 1; m < 64; m <<= 1) s += __shfl_xor(s, m);
    __shared__ float red[2];
    if ((tid & 63) == 0) red[tid >> 6] = s;
    __syncthreads();
    if (tid == 0) nrm[row] = sqrtf(red[0] + red[1]);
}

// ---------------- K3: class histogram ----------------
__global__ __launch_bounds__(512) void k_hist(const int* __restrict__ label,
                                              int* __restrict__ cnt) {
    __shared__ int h[512];
    int tid = threadIdx.x;
    h[tid] = 0;
    __syncthreads();
    for (int i = tid; i < NR; i += 512) atomicAdd(&h[label[i]], 1);
    __syncthreads();
    cnt[tid] = h[tid];
}

// ---------------- K4: main fused GEMM + row reductions ----------------
// grid (16, 64): blockIdx.x = 512-col chunk, blockIdx.y = 128-row block
__global__ __launch_bounds__(256, 2) void k_main(const short* __restrict__ embb,
                                                 const float* __restrict__ sq,
                                                 const int* __restrict__ label,
                                                 u64* __restrict__ pT1, u64* __restrict__ pT2,
                                                 float* __restrict__ pMin, u64* __restrict__ pMax) {
    __shared__ short As[128 * 32];
    __shared__ short Bs[128 * 32];
    __shared__ u64 stT1[256], stT2[256], stMx[256];
    __shared__ float stMn[256];

    const int tid = threadIdx.x;
    const int lane = tid & 63;
    const int wid = tid >> 6;
    const int wm = wid >> 1, wn = wid & 1;
    const int q = lane >> 4, l15 = lane & 15;
    const int i0 = blockIdx.y * 128;
    const int bx = blockIdx.x;

    stT1[tid] = 0; stT2[tid] = 0; stMx[tid] = 0; stMn[tid] = 3.0e38f;
    __syncthreads();

    for (int jt = 0; jt < 4; ++jt) {
        const int j0 = bx * 512 + jt * 128;
        f32x4 acc[4][4];
#pragma unroll
        for (int mi = 0; mi < 4; ++mi)
#pragma unroll
            for (int ni = 0; ni < 4; ++ni) acc[mi][ni] = (f32x4){0.f, 0.f, 0.f, 0.f};

        for (int ks = 0; ks < 32; ++ks) {
            const int k0 = ks * 32;
#pragma unroll
            for (int p = 0; p < 2; ++p) {
                int ci = tid + p * 256;          // 512 chunks of 16B
                int row = ci >> 2, c4 = ci & 3;
                *(int4*)&As[ci * 8] = *(const int4*)&embb[(size_t)(i0 + row) * DE + k0 + c4 * 8];
                *(int4*)&Bs[ci * 8] = *(const int4*)&embb[(size_t)(j0 + row) * DE + k0 + c4 * 8];
            }
            __syncthreads();
            bf16x8 af[4], bf[4];
#pragma unroll
            for (int mi = 0; mi < 4; ++mi)
                af[mi] = *(const bf16x8*)&As[(wm * 64 + mi * 16 + l15) * 32 + q * 8];
#pragma unroll
            for (int ni = 0; ni < 4; ++ni)
                bf[ni] = *(const bf16x8*)&Bs[(wn * 64 + ni * 16 + l15) * 32 + q * 8];
#pragma unroll
            for (int mi = 0; mi < 4; ++mi)
#pragma unroll
                for (int ni = 0; ni < 4; ++ni)
                    acc[mi][ni] = __builtin_amdgcn_mfma_f32_16x16x32_bf16(af[mi], bf[ni], acc[mi][ni], 0, 0, 0);
            __syncthreads();
        }

        // epilogue for this 128-col tile
        int colg[4]; float sqj[4]; int lbj[4];
#pragma unroll
        for (int ni = 0; ni < 4; ++ni) {
            int c = j0 + wn * 64 + ni * 16 + l15;
            colg[ni] = c; sqj[ni] = sq[c]; lbj[ni] = label[c];
        }
#pragma unroll
        for (int mi = 0; mi < 4; ++mi) {
#pragma unroll
            for (int r = 0; r < 4; ++r) {
                int rowl = wm * 64 + mi * 16 + q * 4 + r;
                int rowg = i0 + rowl;
                float sqi = sq[rowg];
                int li = label[rowg];
                u64 p1 = 0, p2 = 0, km = 0;
                float dmin = 3.0e38f;
#pragma unroll
                for (int ni = 0; ni < 4; ++ni) {
                    float dot = acc[mi][ni][r];
                    float d2 = fmaf(-2.0f, dot, sqi + sqj[ni]);
                    d2 = fmaxf(d2, 1e-12f);
                    u64 k = ((u64)__float_as_uint(d2) << 32) | (unsigned)(~colg[ni]);
                    bool same = (li == lbj[ni]);
                    u64 kp = same ? k : 0ull;
                    u64 kn = same ? 0ull : k;
                    float dn = same ? 3.0e38f : d2;
                    u64 mn = umin64(p1, kp);
                    p1 = umax64(p1, kp);
                    p2 = umax64(p2, mn);
                    dmin = fminf(dmin, dn);
                    km = umax64(km, kn);
                }
                // butterfly across the 16 lanes of this quad (rows distinct per quad)
                for (int m = 1; m <= 8; m <<= 1) {
                    u64 o1 = __shfl_xor(p1, m);
                    u64 o2 = __shfl_xor(p2, m);
                    merge_top2(p1, p2, o1, o2);
                    dmin = fminf(dmin, __shfl_xor(dmin, m));
                    km = umax64(km, __shfl_xor(km, m));
                }
                if (l15 == 0) {
                    int s = wn * 128 + rowl;
                    u64 a1 = stT1[s], a2 = stT2[s];
                    merge_top2(a1, a2, p1, p2);
                    stT1[s] = a1; stT2[s] = a2;
                    stMn[s] = fminf(stMn[s], dmin);
                    stMx[s] = umax64(stMx[s], km);
                }
            }
        }
        __syncthreads();
    }

    if (tid < 128) {
        u64 a1 = stT1[tid], a2 = stT2[tid];
        merge_top2(a1, a2, stT1[128 + tid], stT2[128 + tid]);
        float mn = fminf(stMn[tid], stMn[128 + tid]);
        u64 mx = umax64(stMx[tid], stMx[128 + tid]);
        size_t idx = (size_t)(i0 + tid) * NCH + bx;
        pT1[idx] = a1; pT2[idx] = a2; pMin[idx] = mn; pMax[idx] = mx;
    }
}

// ---------------- K5: merge chunk partials, decode ----------------
__global__ __launch_bounds__(256) void k_merge(const u64* __restrict__ pT1, const u64* __restrict__ pT2,
                                               const float* __restrict__ pMin, const u64* __restrict__ pMax,
                                               const int* __restrict__ label, const int* __restrict__ cnt,
                                               float* __restrict__ ap1, float* __restrict__ ap2,
                                               float* __restrict__ an, int* __restrict__ i1,
                                               int* __restrict__ i2) {
    int row = blockIdx.x * 256 + threadIdx.x;
    u64 t1 = 0, t2 = 0, mx = 0;
    float mn = 3.0e38f;
    for (int c = 0; c < NCH; ++c) {
        size_t id = (size_t)row * NCH + c;
        merge_top2(t1, t2, pT1[id], pT2[id]);
        mn = fminf(mn, pMin[id]);
        mx = umax64(mx, pMax[id]);
    }
    int cc = cnt[label[row]];
    float a1 = sqrtf(__uint_as_float((unsigned)(t1 >> 32)));
    int j1 = (int)~(unsigned)(t1 & 0xFFFFFFFFull);
    float a2v; int j2;
    if (cc >= 2) {
        a2v = sqrtf(__uint_as_float((unsigned)(t2 >> 32)));
        j2 = (int)~(unsigned)(t2 & 0xFFFFFFFFull);
    } else {
        // single-member class: ref's top-2 falls back to best (max-dist) negative - BIG
        a2v = sqrtf(__uint_as_float((unsigned)(mx >> 32))) - BIGF;
        j2 = (int)~(unsigned)(mx & 0xFFFFFFFFull);
    }
    ap1[row] = a1; ap2[row] = a2v; an[row] = sqrtf(mn);
    i1[row] = j1; i2[row] = j2;
}

// ---------------- K6: alpha = cos(i, idx) at the two positive indices ----------------
__global__ __launch_bounds__(256) void k_alpha(const float* __restrict__ clot,
                                               const float* __restrict__ nrm,
                                               const int* __restrict__ i1, const int* __restrict__ i2,
                                               float* __restrict__ alpha1, float* __restrict__ alpha2) {
    int tid = threadIdx.x;
    int wid = tid >> 6, lane = tid & 63;
    int row = blockIdx.x * 4 + wid;
    int j1 = i1[row], j2 = i2[row];
    const float4* c4 = (const float4*)clot;
    float s1 = 0.f, s2 = 0.f;
    for (int t = lane; t < DC / 4; t += 64) {
        float4 a = c4[(size_t)row * (DC / 4) + t];
        float4 b1 = c4[(size_t)j1 * (DC / 4) + t];
        float4 b2 = c4[(size_t)j2 * (DC / 4) + t];
        s1 += a.x * b1.x + a.y * b1.y + a.z * b1.z + a.w * b1.w;
        s2 += a.x * b2.x + a.y * b2.y + a.z * b2.z + a.w * b2.w;
    }
    for (int m = 1; m < 64; m <<= 1) { s1 += __shfl_xor(s1, m); s2 += __shfl_xor(s2, m); }
    if (lane == 0) {
        alpha1[row] = s1 / (nrm[row] * nrm[j1]);
        alpha2[row] = s2 / (nrm[row] * nrm[j2]);
    }
}

// ---------------- K7: final loss + prec ----------------
__global__ __launch_bounds__(256) void k_final(const float* __restrict__ ap1, const float* __restrict__ ap2,
                                               const float* __restrict__ an,
                                               const float* __restrict__ alpha1, const float* __restrict__ alpha2,
                                               float* __restrict__ out) {
    int tid = threadIdx.x;
    float sl11 = 0.f, sl13 = 0.f, sp = 0.f;
    for (int row = tid; row < NR; row += 256) {
        float a1 = alpha1[row], a2 = alpha2[row];
        float dap1 = ap1[row], dap2 = ap2[row], dan = an[row];
        float y = (a1 < a2) ? -1.f : 1.f;
        float ym = (a1 == a2) ? 0.f : 1.f;
        float x1 = dap2 * ym;
        float x2 = dap1 * ym + MARG * (a1 - a2 - y);
        sl11 += fmaxf(0.f, -y * (x1 - x2) + MARG);
        float ap1m = dap1 + MARG * (a1 - 1.f);
        sl13 += fmaxf(0.f, -(dan - ap1m) + MARG);
        sp += (dan > ap1m) ? 1.f : 0.f;
    }
    for (int m = 1; m < 64; m <<= 1) {
        sl11 += __shfl_xor(sl11, m);
        sl13 += __shfl_xor(sl13, m);
        sp += __shfl_xor(sp, m);
    }
    __shared__ float r11[4], r13[4], rp[4];
    if ((tid & 63) == 0) { r11[tid >> 6] = sl11; r13[tid >> 6] = sl13; rp[tid >> 6] = sp; }
    __syncthreads();
    if (tid == 0) {
        float t11 = r11[0] + r11[1] + r11[2] + r11[3];
        float t13 = r13[0] + r13[1] + r13[2] + r13[3];
        float tp = rp[0] + rp[1] + rp[2] + rp[3];
        out[0] = 0.1f * (t11 / (float)NR) + t13 / (float)NR;
        out[1] = tp / (float)NR;
    }
}

extern "C" void kernel_launch(void* const* d_in, const int* in_sizes, int n_in,
                              void* d_out, int out_size, void* d_ws, size_t ws_size,
                              hipStream_t stream) {
    const float* emb = (const float*)d_in[0];
    const int* label = (const int*)d_in[1];
    const float* clot = (const float*)d_in[2];
    float* out = (float*)d_out;

    char* ws = (char*)d_ws;
    size_t off = 0;
    auto alloc = [&](size_t bytes) -> char* {
        char* p = ws + off;
        off = (off + bytes + 255) & ~(size_t)255;
        return p;
    };
    short* embb = (short*)alloc((size_t)NR * DE * 2);
    float* sq   = (float*)alloc(NR * 4);
    float* nrm  = (float*)alloc(NR * 4);
    int*   cnt  = (int*)alloc(512 * 4);
    u64*   pT1  = (u64*)alloc((size_t)NR * NCH * 8);
    u64*   pT2  = (u64*)alloc((size_t)NR * NCH * 8);
    u64*   pMax = (u64*)alloc((size_t)NR * NCH * 8);
    float* pMin = (float*)alloc((size_t)NR * NCH * 4);
    float* ap1  = (float*)alloc(NR * 4);
    float* ap2  = (float*)alloc(NR * 4);
    float* an   = (float*)alloc(NR * 4);
    int*   i1   = (int*)alloc(NR * 4);
    int*   i2   = (int*)alloc(NR * 4);
    float* al1  = (float*)alloc(NR * 4);
    float* al2  = (float*)alloc(NR * 4);

    k_prep_emb<<<dim3(NR), dim3(256), 0, stream>>>(emb, embb, sq);
    k_nrm<<<dim3(NR), dim3(128), 0, stream>>>(clot, nrm);
    k_hist<<<dim3(1), dim3(512), 0, stream>>>(label, cnt);
    k_main<<<dim3(NCH, NR / 128), dim3(256), 0, stream>>>(embb, sq, label, pT1, pT2, pMin, pMax);
    k_merge<<<dim3(NR / 256), dim3(256), 0, stream>>>(pT1, pT2, pMin, pMax, label, cnt, ap1, ap2, an, i1, i2);
    k_alpha<<<dim3(NR / 4), dim3(256), 0, stream>>>(clot, nrm, i1, i2, al1, al2);
    k_final<<<dim3(1), dim3(256), 0, stream>>>(ap1, ap2, an, al1, al2, out);
}

// Round 2
// 380.478 us; speedup vs baseline: 1.0506x; 1.0506x over previous
//
#include <hip/hip_runtime.h>
#include <stdint.h>

#define NR 8192
#define DE 1024
#define DC 512
#define NCH 16          // column chunks (8192/512)
#define BIGF 9999999.0f
#define MARG 0.3f

typedef __attribute__((ext_vector_type(8))) short bf16x8;
typedef __attribute__((ext_vector_type(4))) float f32x4;
typedef unsigned long long u64;

typedef __attribute__((address_space(3))) unsigned int lds_u32;
typedef const __attribute__((address_space(1))) unsigned int glb_u32;

static __device__ __forceinline__ void ld_g2l16(const void* g, void* l) {
    __builtin_amdgcn_global_load_lds((glb_u32*)g, (lds_u32*)l, 16, 0, 0);
}

static __device__ __forceinline__ u64 umax64(u64 a, u64 b) { return a > b ? a : b; }
static __device__ __forceinline__ u64 umin64(u64 a, u64 b) { return a < b ? a : b; }

// merge sorted pair (p1>=p2) with sorted pair (o1>=o2) -> top2 of union
static __device__ __forceinline__ void merge_top2(u64& p1, u64& p2, u64 o1, u64 o2) {
    bool a = p1 >= o1;
    u64 hi = a ? p1 : o1;
    u64 lo = a ? o1 : p1;
    u64 s  = a ? p2 : o2;
    p1 = hi;
    p2 = umax64(lo, s);
}

static __device__ __forceinline__ unsigned short f2bf(float x) {
    unsigned u = __float_as_uint(x);
    unsigned r = u + 0x7FFFu + ((u >> 16) & 1u);
    return (unsigned short)(r >> 16);
}

// ---------------- K1: emb -> bf16, sq[i] = ||emb_i||^2 (fp32) ----------------
__global__ __launch_bounds__(256) void k_prep_emb(const float* __restrict__ emb,
                                                  short* __restrict__ embb,
                                                  float* __restrict__ sq) {
    int row = blockIdx.x, tid = threadIdx.x;
    float4 v = ((const float4*)(emb + (size_t)row * DE))[tid];   // 1024/4 = 256 float4
    float s = v.x * v.x + v.y * v.y + v.z * v.z + v.w * v.w;
    ushort4 b;
    b.x = f2bf(v.x); b.y = f2bf(v.y); b.z = f2bf(v.z); b.w = f2bf(v.w);
    *(ushort4*)&embb[(size_t)row * DE + tid * 4] = b;
    for (int m = 1; m < 64; m <<= 1) s += __shfl_xor(s, m);
    __shared__ float red[4];
    if ((tid & 63) == 0) red[tid >> 6] = s;
    __syncthreads();
    if (tid == 0) sq[row] = red[0] + red[1] + red[2] + red[3];
}

// ---------------- K2: nrm[i] = ||clot_i|| ----------------
__global__ __launch_bounds__(128) void k_nrm(const float* __restrict__ clot,
                                             float* __restrict__ nrm) {
    int row = blockIdx.x, tid = threadIdx.x;
    float4 v = ((const float4*)(clot + (size_t)row * DC))[tid];  // 512/4 = 128 float4
    float s = v.x * v.x + v.y * v.y + v.z * v.z + v.w * v.w;
    for (int m = 1; m < 64; m <<= 1) s += __shfl_xor(s, m);
    __shared__ float red[2];
    if ((tid & 63) == 0) red[tid >> 6] = s;
    __syncthreads();
    if (tid == 0) nrm[row] = sqrtf(red[0] + red[1]);
}

// ---------------- K3: class histogram ----------------
__global__ __launch_bounds__(512) void k_hist(const int* __restrict__ label,
                                              int* __restrict__ cnt) {
    __shared__ int h[512];
    int tid = threadIdx.x;
    h[tid] = 0;
    __syncthreads();
    for (int i = tid; i < NR; i += 512) atomicAdd(&h[label[i]], 1);
    __syncthreads();
    cnt[tid] = h[tid];
}

// ---------------- K4: main fused GEMM + row reductions ----------------
// grid (16, 64): blockIdx.x = 512-col chunk, blockIdx.y = 128-row block
__global__ __launch_bounds__(256, 2) void k_main(const short* __restrict__ embb,
                                                 const float* __restrict__ sq,
                                                 const int* __restrict__ label,
                                                 u64* __restrict__ pT1, u64* __restrict__ pT2,
                                                 float* __restrict__ pMin, u64* __restrict__ pMax) {
    __shared__ __align__(16) short As[128 * 32];
    __shared__ __align__(16) short Bs[128 * 32];
    __shared__ u64 stT1[256], stT2[256], stMx[256];
    __shared__ float stMn[256];

    const int tid = threadIdx.x;
    const int lane = tid & 63;
    const int wid = tid >> 6;
    const int wm = wid >> 1, wn = wid & 1;
    const int q = lane >> 4, l15 = lane & 15;
    const int i0 = blockIdx.y * 128;
    const int bx = blockIdx.x;

    stT1[tid] = 0; stT2[tid] = 0; stMx[tid] = 0; stMn[tid] = 3.0e38f;
    __syncthreads();

    const int srow = tid >> 2, sc4 = tid & 3;   // staging: row within 64-row slab, 16B chunk
    const short* gA = embb + (size_t)(i0 + srow) * DE + sc4 * 8;

    for (int jt = 0; jt < 4; ++jt) {
        const int j0 = bx * 512 + jt * 128;
        const short* gB = embb + (size_t)(j0 + srow) * DE + sc4 * 8;
        f32x4 acc[4][4];
#pragma unroll
        for (int mi = 0; mi < 4; ++mi)
#pragma unroll
            for (int ni = 0; ni < 4; ++ni) acc[mi][ni] = (f32x4){0.f, 0.f, 0.f, 0.f};

        for (int ks = 0; ks < 32; ++ks) {
            const int k0 = ks * 32;
            // async global->LDS staging: 4 x 16B per thread (A slab0/1, B slab0/1)
            ld_g2l16(gA + k0, &As[(size_t)tid * 8]);
            ld_g2l16(gA + (size_t)64 * DE + k0, &As[(size_t)(tid + 256) * 8]);
            ld_g2l16(gB + k0, &Bs[(size_t)tid * 8]);
            ld_g2l16(gB + (size_t)64 * DE + k0, &Bs[(size_t)(tid + 256) * 8]);
            __syncthreads();
            bf16x8 af[4], bfr[4];
#pragma unroll
            for (int mi = 0; mi < 4; ++mi)
                af[mi] = *(const bf16x8*)&As[(wm * 64 + mi * 16 + l15) * 32 + q * 8];
#pragma unroll
            for (int ni = 0; ni < 4; ++ni)
                bfr[ni] = *(const bf16x8*)&Bs[(wn * 64 + ni * 16 + l15) * 32 + q * 8];
#pragma unroll
            for (int mi = 0; mi < 4; ++mi)
#pragma unroll
                for (int ni = 0; ni < 4; ++ni)
                    acc[mi][ni] = __builtin_amdgcn_mfma_f32_16x16x32_bf16(af[mi], bfr[ni], acc[mi][ni], 0, 0, 0);
            __syncthreads();
        }

        // epilogue for this 128-col tile
        int colg[4]; float sqj[4]; int lbj[4];
#pragma unroll
        for (int ni = 0; ni < 4; ++ni) {
            int c = j0 + wn * 64 + ni * 16 + l15;
            colg[ni] = c; sqj[ni] = sq[c]; lbj[ni] = label[c];
        }
#pragma unroll
        for (int mi = 0; mi < 4; ++mi) {
#pragma unroll
            for (int r = 0; r < 4; ++r) {
                int rowl = wm * 64 + mi * 16 + q * 4 + r;
                int rowg = i0 + rowl;
                float sqi = sq[rowg];
                int li = label[rowg];
                u64 p1 = 0, p2 = 0, km = 0;
                float dmin = 3.0e38f;
#pragma unroll
                for (int ni = 0; ni < 4; ++ni) {
                    float dot = acc[mi][ni][r];
                    float d2 = fmaf(-2.0f, dot, sqi + sqj[ni]);
                    d2 = fmaxf(d2, 1e-12f);
                    u64 k = ((u64)__float_as_uint(d2) << 32) | (unsigned)(~colg[ni]);
                    bool same = (li == lbj[ni]);
                    u64 kp = same ? k : 0ull;
                    u64 kn = same ? 0ull : k;
                    float dn = same ? 3.0e38f : d2;
                    u64 mn = umin64(p1, kp);
                    p1 = umax64(p1, kp);
                    p2 = umax64(p2, mn);
                    dmin = fminf(dmin, dn);
                    km = umax64(km, kn);
                }
                // butterfly across the 16 lanes of this quad (rows distinct per quad)
                for (int m = 1; m <= 8; m <<= 1) {
                    u64 o1 = __shfl_xor(p1, m);
                    u64 o2 = __shfl_xor(p2, m);
                    merge_top2(p1, p2, o1, o2);
                    dmin = fminf(dmin, __shfl_xor(dmin, m));
                    km = umax64(km, __shfl_xor(km, m));
                }
                if (l15 == 0) {
                    int s = wn * 128 + rowl;
                    u64 a1 = stT1[s], a2 = stT2[s];
                    merge_top2(a1, a2, p1, p2);
                    stT1[s] = a1; stT2[s] = a2;
                    stMn[s] = fminf(stMn[s], dmin);
                    stMx[s] = umax64(stMx[s], km);
                }
            }
        }
        __syncthreads();
    }

    if (tid < 128) {
        u64 a1 = stT1[tid], a2 = stT2[tid];
        merge_top2(a1, a2, stT1[128 + tid], stT2[128 + tid]);
        float mn = fminf(stMn[tid], stMn[128 + tid]);
        u64 mx = umax64(stMx[tid], stMx[128 + tid]);
        size_t idx = (size_t)(i0 + tid) * NCH + bx;
        pT1[idx] = a1; pT2[idx] = a2; pMin[idx] = mn; pMax[idx] = mx;
    }
}

// ---------------- K5: merge chunk partials, decode, alpha dots (fused) ----------------
// one wave per row; grid NR/4 x 256 threads
__global__ __launch_bounds__(256) void k_merge_alpha(const u64* __restrict__ pT1, const u64* __restrict__ pT2,
                                                     const float* __restrict__ pMin, const u64* __restrict__ pMax,
                                                     const int* __restrict__ label, const int* __restrict__ cnt,
                                                     const float* __restrict__ clot, const float* __restrict__ nrm,
                                                     float* __restrict__ ap1, float* __restrict__ ap2,
                                                     float* __restrict__ an,
                                                     float* __restrict__ alpha1, float* __restrict__ alpha2) {
    int wid = threadIdx.x >> 6, lane = threadIdx.x & 63;
    int row = blockIdx.x * 4 + wid;
    u64 t1 = 0, t2 = 0, mx = 0;
    float mn = 3.0e38f;
    if (lane < NCH) {
        size_t id = (size_t)row * NCH + lane;
        t1 = pT1[id]; t2 = pT2[id]; mn = pMin[id]; mx = pMax[id];
    }
    for (int m = 1; m <= 8; m <<= 1) {   // xor<16 stays within the 16-lane group
        u64 o1 = __shfl_xor(t1, m), o2 = __shfl_xor(t2, m);
        merge_top2(t1, t2, o1, o2);
        mn = fminf(mn, __shfl_xor(mn, m));
        mx = umax64(mx, __shfl_xor(mx, m));
    }
    t1 = __shfl(t1, 0); t2 = __shfl(t2, 0);
    mx = __shfl(mx, 0); mn = __shfl(mn, 0);

    int cc = cnt[label[row]];
    float a1 = sqrtf(__uint_as_float((unsigned)(t1 >> 32)));
    int j1 = (int)~(unsigned)(t1 & 0xFFFFFFFFull);
    float a2v; int j2;
    if (cc >= 2) {
        a2v = sqrtf(__uint_as_float((unsigned)(t2 >> 32)));
        j2 = (int)~(unsigned)(t2 & 0xFFFFFFFFull);
    } else {
        // single-member class: ref's top-2 falls back to best (max-dist) negative - BIG
        a2v = sqrtf(__uint_as_float((unsigned)(mx >> 32))) - BIGF;
        j2 = (int)~(unsigned)(mx & 0xFFFFFFFFull);
    }

    // alpha dots: cos(row, j1), cos(row, j2)
    const float4* c4 = (const float4*)clot;
    float s1 = 0.f, s2 = 0.f;
    for (int t = lane; t < DC / 4; t += 64) {
        float4 a = c4[(size_t)row * (DC / 4) + t];
        float4 b1 = c4[(size_t)j1 * (DC / 4) + t];
        float4 b2 = c4[(size_t)j2 * (DC / 4) + t];
        s1 += a.x * b1.x + a.y * b1.y + a.z * b1.z + a.w * b1.w;
        s2 += a.x * b2.x + a.y * b2.y + a.z * b2.z + a.w * b2.w;
    }
    for (int m = 1; m < 64; m <<= 1) { s1 += __shfl_xor(s1, m); s2 += __shfl_xor(s2, m); }
    if (lane == 0) {
        ap1[row] = a1; ap2[row] = a2v; an[row] = sqrtf(mn);
        alpha1[row] = s1 / (nrm[row] * nrm[j1]);
        alpha2[row] = s2 / (nrm[row] * nrm[j2]);
    }
}

// ---------------- K7: final loss + prec ----------------
__global__ __launch_bounds__(256) void k_final(const float* __restrict__ ap1, const float* __restrict__ ap2,
                                               const float* __restrict__ an,
                                               const float* __restrict__ alpha1, const float* __restrict__ alpha2,
                                               float* __restrict__ out) {
    int tid = threadIdx.x;
    float sl11 = 0.f, sl13 = 0.f, sp = 0.f;
    for (int row = tid; row < NR; row += 256) {
        float a1 = alpha1[row], a2 = alpha2[row];
        float dap1 = ap1[row], dap2 = ap2[row], dan = an[row];
        float y = (a1 < a2) ? -1.f : 1.f;
        float ym = (a1 == a2) ? 0.f : 1.f;
        float x1 = dap2 * ym;
        float x2 = dap1 * ym + MARG * (a1 - a2 - y);
        sl11 += fmaxf(0.f, -y * (x1 - x2) + MARG);
        float ap1m = dap1 + MARG * (a1 - 1.f);
        sl13 += fmaxf(0.f, -(dan - ap1m) + MARG);
        sp += (dan > ap1m) ? 1.f : 0.f;
    }
    for (int m = 1; m < 64; m <<= 1) {
        sl11 += __shfl_xor(sl11, m);
        sl13 += __shfl_xor(sl13, m);
        sp += __shfl_xor(sp, m);
    }
    __shared__ float r11[4], r13[4], rp[4];
    if ((tid & 63) == 0) { r11[tid >> 6] = sl11; r13[tid >> 6] = sl13; rp[tid >> 6] = sp; }
    __syncthreads();
    if (tid == 0) {
        float t11 = r11[0] + r11[1] + r11[2] + r11[3];
        float t13 = r13[0] + r13[1] + r13[2] + r13[3];
        float tp = rp[0] + rp[1] + rp[2] + rp[3];
        out[0] = 0.1f * (t11 / (float)NR) + t13 / (float)NR;
        out[1] = tp / (float)NR;
    }
}

extern "C" void kernel_launch(void* const* d_in, const int* in_sizes, int n_in,
                              void* d_out, int out_size, void* d_ws, size_t ws_size,
                              hipStream_t stream) {
    const float* emb = (const float*)d_in[0];
    const int* label = (const int*)d_in[1];
    const float* clot = (const float*)d_in[2];
    float* out = (float*)d_out;

    char* ws = (char*)d_ws;
    size_t off = 0;
    auto alloc = [&](size_t bytes) -> char* {
        char* p = ws + off;
        off = (off + bytes + 255) & ~(size_t)255;
        return p;
    };
    short* embb = (short*)alloc((size_t)NR * DE * 2);
    float* sq   = (float*)alloc(NR * 4);
    float* nrm  = (float*)alloc(NR * 4);
    int*   cnt  = (int*)alloc(512 * 4);
    u64*   pT1  = (u64*)alloc((size_t)NR * NCH * 8);
    u64*   pT2  = (u64*)alloc((size_t)NR * NCH * 8);
    u64*   pMax = (u64*)alloc((size_t)NR * NCH * 8);
    float* pMin = (float*)alloc((size_t)NR * NCH * 4);
    float* ap1  = (float*)alloc(NR * 4);
    float* ap2  = (float*)alloc(NR * 4);
    float* an   = (float*)alloc(NR * 4);
    float* al1  = (float*)alloc(NR * 4);
    float* al2  = (float*)alloc(NR * 4);

    k_prep_emb<<<dim3(NR), dim3(256), 0, stream>>>(emb, embb, sq);
    k_nrm<<<dim3(NR), dim3(128), 0, stream>>>(clot, nrm);
    k_hist<<<dim3(1), dim3(512), 0, stream>>>(label, cnt);
    k_main<<<dim3(NCH, NR / 128), dim3(256), 0, stream>>>(embb, sq, label, pT1, pT2, pMin, pMax);
    k_merge_alpha<<<dim3(NR / 4), dim3(256), 0, stream>>>(pT1, pT2, pMin, pMax, label, cnt,
                                                          clot, nrm, ap1, ap2, an, al1, al2);
    k_final<<<dim3(1), dim3(256), 0, stream>>>(ap1, ap2, an, al1, al2, out);
}

// Round 3
// 375.686 us; speedup vs baseline: 1.0640x; 1.0128x over previous
//
#include <hip/hip_runtime.h>
#include <stdint.h>

#define NR 8192
#define DE 1024
#define DC 512
#define NCH 16          // column chunks (8192/512)
#define BIGF 9999999.0f
#define MARG 0.3f
#define NEGI -3.0e38f
#define POSI 3.0e38f

typedef __attribute__((ext_vector_type(8))) short bf16x8;
typedef __attribute__((ext_vector_type(4))) float f32x4;

typedef __attribute__((address_space(3))) unsigned int lds_u32;
typedef const __attribute__((address_space(1))) unsigned int glb_u32;

static __device__ __forceinline__ void ld_g2l16(const void* g, void* l) {
    __builtin_amdgcn_global_load_lds((glb_u32*)g, (lds_u32*)l, 16, 0, 0);
}

// merge sorted pair (v1>=v2) with sorted pair (o1>=o2) -> top2 of union (with indices)
static __device__ __forceinline__ void merge_top2(float& v1, int& i1, float& v2, int& i2,
                                                  float o1, int oi1, float o2, int oi2) {
    bool a = o1 > v1;
    float hi = a ? o1 : v1;  int hii = a ? oi1 : i1;
    float lo = a ? v1 : o1;  int loi = a ? i1 : oi1;
    float s  = a ? o2 : v2;  int si  = a ? oi2 : i2;
    bool b = s > lo;
    v1 = hi; i1 = hii;
    v2 = b ? s : lo; i2 = b ? si : loi;
}

static __device__ __forceinline__ unsigned short f2bf(float x) {
    unsigned u = __float_as_uint(x);
    unsigned r = u + 0x7FFFu + ((u >> 16) & 1u);
    return (unsigned short)(r >> 16);
}

// ---------------- K1: emb -> bf16, sq[i] = ||emb_i||^2 (fp32) ----------------
__global__ __launch_bounds__(256) void k_prep_emb(const float* __restrict__ emb,
                                                  short* __restrict__ embb,
                                                  float* __restrict__ sq) {
    int row = blockIdx.x, tid = threadIdx.x;
    float4 v = ((const float4*)(emb + (size_t)row * DE))[tid];   // 1024/4 = 256 float4
    float s = v.x * v.x + v.y * v.y + v.z * v.z + v.w * v.w;
    ushort4 b;
    b.x = f2bf(v.x); b.y = f2bf(v.y); b.z = f2bf(v.z); b.w = f2bf(v.w);
    *(ushort4*)&embb[(size_t)row * DE + tid * 4] = b;
    for (int m = 1; m < 64; m <<= 1) s += __shfl_xor(s, m);
    __shared__ float red[4];
    if ((tid & 63) == 0) red[tid >> 6] = s;
    __syncthreads();
    if (tid == 0) sq[row] = red[0] + red[1] + red[2] + red[3];
}

// ---------------- K3: class histogram ----------------
__global__ __launch_bounds__(512) void k_hist(const int* __restrict__ label,
                                              int* __restrict__ cnt) {
    __shared__ int h[512];
    int tid = threadIdx.x;
    h[tid] = 0;
    __syncthreads();
    for (int i = tid; i < NR; i += 512) atomicAdd(&h[label[i]], 1);
    __syncthreads();
    cnt[tid] = h[tid];
}

// ---------------- K4: main fused GEMM + row reductions ----------------
// grid (16, 64): blockIdx.x = 512-col chunk, blockIdx.y = 128-row block
__global__ __launch_bounds__(256, 3) void k_main(const short* __restrict__ embb,
                                                 const float* __restrict__ sq,
                                                 const int* __restrict__ label,
                                                 float* __restrict__ pV1, int* __restrict__ pI1,
                                                 float* __restrict__ pV2, int* __restrict__ pI2,
                                                 float* __restrict__ pMn,
                                                 float* __restrict__ pKv, int* __restrict__ pKi) {
    __shared__ __align__(16) short As[128 * 32];
    __shared__ __align__(16) short Bs[128 * 32];
    __shared__ float stV1[256], stV2[256], stMn[256], stKv[256];
    __shared__ int stI1[256], stI2[256], stKi[256];

    const int tid = threadIdx.x;
    const int lane = tid & 63;
    const int wid = tid >> 6;
    const int wm = wid >> 1, wn = wid & 1;
    const int q = lane >> 4, l15 = lane & 15;
    const int i0 = blockIdx.y * 128;
    const int bx = blockIdx.x;

    stV1[tid] = NEGI; stV2[tid] = NEGI; stMn[tid] = POSI; stKv[tid] = NEGI;
    stI1[tid] = 0; stI2[tid] = 0; stKi[tid] = 0;
    __syncthreads();

    const int srow = tid >> 2, sc4 = tid & 3;   // staging: row within 64-row slab, 16B chunk
    const short* gA = embb + (size_t)(i0 + srow) * DE + sc4 * 8;

    for (int jt = 0; jt < 4; ++jt) {
        const int j0 = bx * 512 + jt * 128;
        const short* gB = embb + (size_t)(j0 + srow) * DE + sc4 * 8;
        f32x4 acc[4][4];
#pragma unroll
        for (int mi = 0; mi < 4; ++mi)
#pragma unroll
            for (int ni = 0; ni < 4; ++ni) acc[mi][ni] = (f32x4){0.f, 0.f, 0.f, 0.f};

        for (int ks = 0; ks < 32; ++ks) {
            const int k0 = ks * 32;
            // async global->LDS staging: 4 x 16B per thread (A slab0/1, B slab0/1)
            ld_g2l16(gA + k0, &As[(size_t)tid * 8]);
            ld_g2l16(gA + (size_t)64 * DE + k0, &As[(size_t)(tid + 256) * 8]);
            ld_g2l16(gB + k0, &Bs[(size_t)tid * 8]);
            ld_g2l16(gB + (size_t)64 * DE + k0, &Bs[(size_t)(tid + 256) * 8]);
            __syncthreads();
            bf16x8 af[4], bfr[4];
#pragma unroll
            for (int mi = 0; mi < 4; ++mi)
                af[mi] = *(const bf16x8*)&As[(wm * 64 + mi * 16 + l15) * 32 + q * 8];
#pragma unroll
            for (int ni = 0; ni < 4; ++ni)
                bfr[ni] = *(const bf16x8*)&Bs[(wn * 64 + ni * 16 + l15) * 32 + q * 8];
#pragma unroll
            for (int mi = 0; mi < 4; ++mi)
#pragma unroll
                for (int ni = 0; ni < 4; ++ni)
                    acc[mi][ni] = __builtin_amdgcn_mfma_f32_16x16x32_bf16(af[mi], bfr[ni], acc[mi][ni], 0, 0, 0);
            __syncthreads();
        }

        // epilogue for this 128-col tile
        int colg[4]; float sqj[4]; int lbj[4];
#pragma unroll
        for (int ni = 0; ni < 4; ++ni) {
            int c = j0 + wn * 64 + ni * 16 + l15;
            colg[ni] = c; sqj[ni] = sq[c]; lbj[ni] = label[c];
        }
#pragma unroll
        for (int mi = 0; mi < 4; ++mi) {
#pragma unroll
            for (int r = 0; r < 4; ++r) {
                int rowl = wm * 64 + mi * 16 + q * 4 + r;
                int rowg = i0 + rowl;
                float sqi = sq[rowg];
                int li = label[rowg];
                float v1 = NEGI, v2 = NEGI, dmn = POSI, kv = NEGI;
                int i1 = 0, i2 = 0, ki = 0;
#pragma unroll
                for (int ni = 0; ni < 4; ++ni) {
                    float dot = acc[mi][ni][r];
                    float d2 = fmaf(-2.0f, dot, sqi + sqj[ni]);
                    d2 = fmaxf(d2, 1e-12f);
                    bool same = (li == lbj[ni]);
                    float kp = same ? d2 : NEGI;
                    // insert kp into sorted (v1,v2)
                    bool c1 = kp > v1, c2 = kp > v2;
                    v2 = c1 ? v1 : (c2 ? kp : v2);
                    i2 = c1 ? i1 : (c2 ? colg[ni] : i2);
                    v1 = c1 ? kp : v1;
                    i1 = c1 ? colg[ni] : i1;
                    dmn = fminf(dmn, same ? POSI : d2);
                    float kn = same ? NEGI : d2;
                    bool ck = kn > kv;
                    kv = ck ? kn : kv; ki = ck ? colg[ni] : ki;
                }
                // butterfly across the 16 lanes of this quad (rows distinct per quad)
                for (int m = 1; m <= 8; m <<= 1) {
                    float o1 = __shfl_xor(v1, m); int oi1 = __shfl_xor(i1, m);
                    float o2 = __shfl_xor(v2, m); int oi2 = __shfl_xor(i2, m);
                    merge_top2(v1, i1, v2, i2, o1, oi1, o2, oi2);
                    dmn = fminf(dmn, __shfl_xor(dmn, m));
                    float ok = __shfl_xor(kv, m); int oki = __shfl_xor(ki, m);
                    bool ck = ok > kv;
                    kv = ck ? ok : kv; ki = ck ? oki : ki;
                }
                if (l15 == 0) {
                    int s = wn * 128 + rowl;
                    float a1 = stV1[s], a2 = stV2[s];
                    int ai1 = stI1[s], ai2 = stI2[s];
                    merge_top2(a1, ai1, a2, ai2, v1, i1, v2, i2);
                    stV1[s] = a1; stI1[s] = ai1; stV2[s] = a2; stI2[s] = ai2;
                    stMn[s] = fminf(stMn[s], dmn);
                    if (kv > stKv[s]) { stKv[s] = kv; stKi[s] = ki; }
                }
            }
        }
        __syncthreads();
    }

    if (tid < 128) {
        float a1 = stV1[tid], a2 = stV2[tid];
        int ai1 = stI1[tid], ai2 = stI2[tid];
        merge_top2(a1, ai1, a2, ai2, stV1[128 + tid], stI1[128 + tid], stV2[128 + tid], stI2[128 + tid]);
        float mn = fminf(stMn[tid], stMn[128 + tid]);
        float kv = stKv[tid]; int ki = stKi[tid];
        if (stKv[128 + tid] > kv) { kv = stKv[128 + tid]; ki = stKi[128 + tid]; }
        size_t idx = (size_t)(i0 + tid) * NCH + bx;
        pV1[idx] = a1; pI1[idx] = ai1; pV2[idx] = a2; pI2[idx] = ai2;
        pMn[idx] = mn; pKv[idx] = kv; pKi[idx] = ki;
    }
}

// ---------------- K5: merge chunk partials, decode, norms + alpha dots (fused) ----------------
// one wave per row; grid NR/4 x 256 threads
__global__ __launch_bounds__(256) void k_merge_alpha(const float* __restrict__ pV1, const int* __restrict__ pI1,
                                                     const float* __restrict__ pV2, const int* __restrict__ pI2,
                                                     const float* __restrict__ pMn,
                                                     const float* __restrict__ pKv, const int* __restrict__ pKi,
                                                     const int* __restrict__ label, const int* __restrict__ cnt,
                                                     const float* __restrict__ clot,
                                                     float* __restrict__ ap1, float* __restrict__ ap2,
                                                     float* __restrict__ an,
                                                     float* __restrict__ alpha1, float* __restrict__ alpha2) {
    int wid = threadIdx.x >> 6, lane = threadIdx.x & 63;
    int row = blockIdx.x * 4 + wid;
    float v1 = NEGI, v2 = NEGI, mn = POSI, kv = NEGI;
    int i1 = 0, i2 = 0, ki = 0;
    if (lane < NCH) {
        size_t id = (size_t)row * NCH + lane;
        v1 = pV1[id]; i1 = pI1[id]; v2 = pV2[id]; i2 = pI2[id];
        mn = pMn[id]; kv = pKv[id]; ki = pKi[id];
    }
    for (int m = 1; m <= 8; m <<= 1) {   // xor<16 stays within the 16-lane group
        float o1 = __shfl_xor(v1, m); int oi1 = __shfl_xor(i1, m);
        float o2 = __shfl_xor(v2, m); int oi2 = __shfl_xor(i2, m);
        merge_top2(v1, i1, v2, i2, o1, oi1, o2, oi2);
        mn = fminf(mn, __shfl_xor(mn, m));
        float ok = __shfl_xor(kv, m); int oki = __shfl_xor(ki, m);
        bool ck = ok > kv;
        kv = ck ? ok : kv; ki = ck ? oki : ki;
    }
    v1 = __shfl(v1, 0); i1 = __shfl(i1, 0);
    v2 = __shfl(v2, 0); i2 = __shfl(i2, 0);
    mn = __shfl(mn, 0); kv = __shfl(kv, 0); ki = __shfl(ki, 0);

    int cc = cnt[label[row]];
    float a1 = sqrtf(v1);
    int j1 = i1;
    float a2v; int j2;
    if (cc >= 2) {
        a2v = sqrtf(v2);
        j2 = i2;
    } else {
        // single-member class: ref's top-2 falls back to best (max-dist) negative - BIG
        a2v = sqrtf(kv) - BIGF;
        j2 = ki;
    }

    // alpha dots + norms: cos(row, j1), cos(row, j2)
    const float4* c4 = (const float4*)clot;
    float s1 = 0.f, s2 = 0.f, n0 = 0.f, n1 = 0.f, n2 = 0.f;
    for (int t = lane; t < DC / 4; t += 64) {
        float4 a = c4[(size_t)row * (DC / 4) + t];
        float4 b1 = c4[(size_t)j1 * (DC / 4) + t];
        float4 b2 = c4[(size_t)j2 * (DC / 4) + t];
        s1 += a.x * b1.x + a.y * b1.y + a.z * b1.z + a.w * b1.w;
        s2 += a.x * b2.x + a.y * b2.y + a.z * b2.z + a.w * b2.w;
        n0 += a.x * a.x + a.y * a.y + a.z * a.z + a.w * a.w;
        n1 += b1.x * b1.x + b1.y * b1.y + b1.z * b1.z + b1.w * b1.w;
        n2 += b2.x * b2.x + b2.y * b2.y + b2.z * b2.z + b2.w * b2.w;
    }
    for (int m = 1; m < 64; m <<= 1) {
        s1 += __shfl_xor(s1, m); s2 += __shfl_xor(s2, m);
        n0 += __shfl_xor(n0, m); n1 += __shfl_xor(n1, m); n2 += __shfl_xor(n2, m);
    }
    if (lane == 0) {
        ap1[row] = a1; ap2[row] = a2v; an[row] = sqrtf(mn);
        alpha1[row] = s1 / (sqrtf(n0) * sqrtf(n1));
        alpha2[row] = s2 / (sqrtf(n0) * sqrtf(n2));
    }
}

// ---------------- K7: final loss + prec ----------------
__global__ __launch_bounds__(256) void k_final(const float* __restrict__ ap1, const float* __restrict__ ap2,
                                               const float* __restrict__ an,
                                               const float* __restrict__ alpha1, const float* __restrict__ alpha2,
                                               float* __restrict__ out) {
    int tid = threadIdx.x;
    float sl11 = 0.f, sl13 = 0.f, sp = 0.f;
    for (int row = tid; row < NR; row += 256) {
        float a1 = alpha1[row], a2 = alpha2[row];
        float dap1 = ap1[row], dap2 = ap2[row], dan = an[row];
        float y = (a1 < a2) ? -1.f : 1.f;
        float ym = (a1 == a2) ? 0.f : 1.f;
        float x1 = dap2 * ym;
        float x2 = dap1 * ym + MARG * (a1 - a2 - y);
        sl11 += fmaxf(0.f, -y * (x1 - x2) + MARG);
        float ap1m = dap1 + MARG * (a1 - 1.f);
        sl13 += fmaxf(0.f, -(dan - ap1m) + MARG);
        sp += (dan > ap1m) ? 1.f : 0.f;
    }
    for (int m = 1; m < 64; m <<= 1) {
        sl11 += __shfl_xor(sl11, m);
        sl13 += __shfl_xor(sl13, m);
        sp += __shfl_xor(sp, m);
    }
    __shared__ float r11[4], r13[4], rp[4];
    if ((tid & 63) == 0) { r11[tid >> 6] = sl11; r13[tid >> 6] = sl13; rp[tid >> 6] = sp; }
    __syncthreads();
    if (tid == 0) {
        float t11 = r11[0] + r11[1] + r11[2] + r11[3];
        float t13 = r13[0] + r13[1] + r13[2] + r13[3];
        float tp = rp[0] + rp[1] + rp[2] + rp[3];
        out[0] = 0.1f * (t11 / (float)NR) + t13 / (float)NR;
        out[1] = tp / (float)NR;
    }
}

extern "C" void kernel_launch(void* const* d_in, const int* in_sizes, int n_in,
                              void* d_out, int out_size, void* d_ws, size_t ws_size,
                              hipStream_t stream) {
    const float* emb = (const float*)d_in[0];
    const int* label = (const int*)d_in[1];
    const float* clot = (const float*)d_in[2];
    float* out = (float*)d_out;

    char* ws = (char*)d_ws;
    size_t off = 0;
    auto alloc = [&](size_t bytes) -> char* {
        char* p = ws + off;
        off = (off + bytes + 255) & ~(size_t)255;
        return p;
    };
    short* embb = (short*)alloc((size_t)NR * DE * 2);
    float* sq   = (float*)alloc(NR * 4);
    int*   cnt  = (int*)alloc(512 * 4);
    float* pV1  = (float*)alloc((size_t)NR * NCH * 4);
    int*   pI1  = (int*)alloc((size_t)NR * NCH * 4);
    float* pV2  = (float*)alloc((size_t)NR * NCH * 4);
    int*   pI2  = (int*)alloc((size_t)NR * NCH * 4);
    float* pMn  = (float*)alloc((size_t)NR * NCH * 4);
    float* pKv  = (float*)alloc((size_t)NR * NCH * 4);
    int*   pKi  = (int*)alloc((size_t)NR * NCH * 4);
    float* ap1  = (float*)alloc(NR * 4);
    float* ap2  = (float*)alloc(NR * 4);
    float* an   = (float*)alloc(NR * 4);
    float* al1  = (float*)alloc(NR * 4);
    float* al2  = (float*)alloc(NR * 4);

    k_prep_emb<<<dim3(NR), dim3(256), 0, stream>>>(emb, embb, sq);
    k_hist<<<dim3(1), dim3(512), 0, stream>>>(label, cnt);
    k_main<<<dim3(NCH, NR / 128), dim3(256), 0, stream>>>(embb, sq, label,
                                                          pV1, pI1, pV2, pI2, pMn, pKv, pKi);
    k_merge_alpha<<<dim3(NR / 4), dim3(256), 0, stream>>>(pV1, pI1, pV2, pI2, pMn, pKv, pKi,
                                                          label, cnt, clot,
                                                          ap1, ap2, an, al1, al2);
    k_final<<<dim3(1), dim3(256), 0, stream>>>(ap1, ap2, an, al1, al2, out);
}

// Round 4
// 300.539 us; speedup vs baseline: 1.3301x; 1.2500x over previous
//
#include <hip/hip_runtime.h>
#include <stdint.h>

#define NR 8192
#define DE 1024
#define DC 512
#define NCH 16          // column chunks (8192/512)
#define BIGF 9999999.0f
#define MARG 0.3f
#define NEGI -3.0e38f
#define POSI 3.0e38f

typedef __attribute__((ext_vector_type(8))) short bf16x8;
typedef __attribute__((ext_vector_type(4))) float f32x4;

typedef __attribute__((address_space(3))) unsigned int lds_u32;
typedef const __attribute__((address_space(1))) unsigned int glb_u32;

static __device__ __forceinline__ void ld_g2l16(const void* g, void* l) {
    __builtin_amdgcn_global_load_lds((glb_u32*)g, (lds_u32*)l, 16, 0, 0);
}

// merge sorted pair (v1>=v2) with sorted pair (o1>=o2) -> top2 of union (with indices)
static __device__ __forceinline__ void merge_top2(float& v1, int& i1, float& v2, int& i2,
                                                  float o1, int oi1, float o2, int oi2) {
    bool a = o1 > v1;
    float hi = a ? o1 : v1;  int hii = a ? oi1 : i1;
    float lo = a ? v1 : o1;  int loi = a ? i1 : oi1;
    float s  = a ? o2 : v2;  int si  = a ? oi2 : i2;
    bool b = s > lo;
    v1 = hi; i1 = hii;
    v2 = b ? s : lo; i2 = b ? si : loi;
}

static __device__ __forceinline__ unsigned short f2bf(float x) {
    unsigned u = __float_as_uint(x);
    unsigned r = u + 0x7FFFu + ((u >> 16) & 1u);
    return (unsigned short)(r >> 16);
}

// ---------------- K1: emb -> bf16, sq[i] = ||emb_i||^2 (fp32) ----------------
__global__ __launch_bounds__(256) void k_prep_emb(const float* __restrict__ emb,
                                                  short* __restrict__ embb,
                                                  float* __restrict__ sq) {
    int row = blockIdx.x, tid = threadIdx.x;
    float4 v = ((const float4*)(emb + (size_t)row * DE))[tid];   // 1024/4 = 256 float4
    float s = v.x * v.x + v.y * v.y + v.z * v.z + v.w * v.w;
    ushort4 b;
    b.x = f2bf(v.x); b.y = f2bf(v.y); b.z = f2bf(v.z); b.w = f2bf(v.w);
    *(ushort4*)&embb[(size_t)row * DE + tid * 4] = b;
    for (int m = 1; m < 64; m <<= 1) s += __shfl_xor(s, m);
    __shared__ float red[4];
    if ((tid & 63) == 0) red[tid >> 6] = s;
    __syncthreads();
    if (tid == 0) sq[row] = red[0] + red[1] + red[2] + red[3];
}

// ---------------- K3: class histogram ----------------
__global__ __launch_bounds__(512) void k_hist(const int* __restrict__ label,
                                              int* __restrict__ cnt) {
    __shared__ int h[512];
    int tid = threadIdx.x;
    h[tid] = 0;
    __syncthreads();
    for (int i = tid; i < NR; i += 512) atomicAdd(&h[label[i]], 1);
    __syncthreads();
    cnt[tid] = h[tid];
}

// ---------------- K4: main fused GEMM + row reductions ----------------
// grid (16, 64): blockIdx.x = 512-col chunk, blockIdx.y = 128-row block
// Wave tile: 32 rows x 128 cols (acc[2][8]); per-row reduction state lives in
// registers across all 4 jt tiles; butterfly once at the end.
// LDS XOR swizzle: slot (row, c) holds global 16B-chunk c ^ ((row>>1)&3)
//   -> ds_read_b128 bank-start = 16(l15&1) + 4(q^((l15>>1)&3)): 2 lanes/bank, conflict-free.
__global__ __launch_bounds__(256, 2) void k_main(const short* __restrict__ embb,
                                                 const float* __restrict__ sq,
                                                 const int* __restrict__ label,
                                                 float* __restrict__ pV1, int* __restrict__ pI1,
                                                 float* __restrict__ pV2, int* __restrict__ pI2,
                                                 float* __restrict__ pMn,
                                                 float* __restrict__ pKv, int* __restrict__ pKi) {
    __shared__ __align__(16) short As[128 * 32];
    __shared__ __align__(16) short Bs[128 * 32];

    const int tid = threadIdx.x;
    const int lane = tid & 63;
    const int w = tid >> 6;
    const int q = lane >> 4, l15 = lane & 15;
    const int i0 = blockIdx.y * 128;
    const int bx = blockIdx.x;

    // staging source swizzle: slot rr = tid>>2, c = tid&3 -> global chunk g
    const int srow = tid >> 2;
    const int g = (tid & 3) ^ ((tid >> 3) & 3);
    const short* gA = embb + (size_t)(i0 + srow) * DE + g * 8;
    const short* gB = embb + (size_t)(bx * 512 + srow) * DE + g * 8;

    // fragment read swizzle (same for all mi/ni since row base is mult of 16)
    const int pxor = q ^ ((l15 >> 1) & 3);

    // per-row reduction state: p = mi*4 + r -> row = i0 + w*32 + mi*16 + q*4 + r
    float v1[8], v2[8], mnn[8], kvv[8], sqi[8];
    int i1a[8], i2a[8], kia[8], lia[8];
#pragma unroll
    for (int p = 0; p < 8; ++p) {
        v1[p] = NEGI; v2[p] = NEGI; mnn[p] = POSI; kvv[p] = NEGI;
        i1a[p] = 0; i2a[p] = 0; kia[p] = 0;
        int rowg = i0 + w * 32 + (p >> 2) * 16 + q * 4 + (p & 3);
        sqi[p] = sq[rowg]; lia[p] = label[rowg];
    }

    auto stage = [&](int koff, const short* gBb) {
        ld_g2l16(gA + koff, &As[(size_t)tid * 8]);
        ld_g2l16(gA + (size_t)64 * DE + koff, &As[(size_t)(tid + 256) * 8]);
        ld_g2l16(gBb + koff, &Bs[(size_t)tid * 8]);
        ld_g2l16(gBb + (size_t)64 * DE + koff, &Bs[(size_t)(tid + 256) * 8]);
    };

    stage(0, gB);   // prefetch (jt=0, ks=0)

    for (int jt = 0; jt < 4; ++jt) {
        const int j0 = bx * 512 + jt * 128;
        f32x4 acc[2][8];
#pragma unroll
        for (int mi = 0; mi < 2; ++mi)
#pragma unroll
            for (int ni = 0; ni < 8; ++ni) acc[mi][ni] = (f32x4){0.f, 0.f, 0.f, 0.f};

        for (int ks = 0; ks < 32; ++ks) {
            __syncthreads();          // staging visible (vmcnt drain)
            bf16x8 af[2], bfr[8];
#pragma unroll
            for (int mi = 0; mi < 2; ++mi)
                af[mi] = *(const bf16x8*)&As[(w * 32 + mi * 16 + l15) * 32 + pxor * 8];
#pragma unroll
            for (int ni = 0; ni < 8; ++ni)
                bfr[ni] = *(const bf16x8*)&Bs[(ni * 16 + l15) * 32 + pxor * 8];
#pragma unroll
            for (int mi = 0; mi < 2; ++mi)
#pragma unroll
                for (int ni = 0; ni < 8; ++ni)
                    acc[mi][ni] = __builtin_amdgcn_mfma_f32_16x16x32_bf16(af[mi], bfr[ni], acc[mi][ni], 0, 0, 0);
            __syncthreads();          // all reads done before next staging writes
            if (ks < 31) {
                stage((ks + 1) * 32, gB);
            } else if (jt < 3) {
                gB += (size_t)128 * DE;
                stage(0, gB);         // prefetch next jt; overlaps insert phase below
            }
        }

        // insert this jt's 128 cols into register state (overlaps in-flight DMA)
        float sqj[8]; int lbj[8], colg[8];
#pragma unroll
        for (int ni = 0; ni < 8; ++ni) {
            colg[ni] = j0 + ni * 16 + l15;
            sqj[ni] = sq[colg[ni]]; lbj[ni] = label[colg[ni]];
        }
#pragma unroll
        for (int mi = 0; mi < 2; ++mi) {
#pragma unroll
            for (int r = 0; r < 4; ++r) {
                const int p = mi * 4 + r;
                float lv1 = v1[p], lv2 = v2[p], lmn = mnn[p], lkv = kvv[p];
                int li1 = i1a[p], li2 = i2a[p], lki = kia[p];
                const float si = sqi[p]; const int li = lia[p];
#pragma unroll
                for (int ni = 0; ni < 8; ++ni) {
                    float d2 = fmaf(-2.0f, acc[mi][ni][r], si + sqj[ni]);
                    d2 = fmaxf(d2, 1e-12f);
                    bool same = (li == lbj[ni]);
                    float kp = same ? d2 : NEGI;
                    bool c1 = kp > lv1, c2 = kp > lv2;
                    lv2 = c1 ? lv1 : (c2 ? kp : lv2);
                    li2 = c1 ? li1 : (c2 ? colg[ni] : li2);
                    lv1 = c1 ? kp : lv1;
                    li1 = c1 ? colg[ni] : li1;
                    lmn = fminf(lmn, same ? POSI : d2);
                    float kn = same ? NEGI : d2;
                    bool ck = kn > lkv;
                    lkv = ck ? kn : lkv; lki = ck ? colg[ni] : lki;
                }
                v1[p] = lv1; v2[p] = lv2; mnn[p] = lmn; kvv[p] = lkv;
                i1a[p] = li1; i2a[p] = li2; kia[p] = lki;
            }
        }
    }

    // final butterfly over the 16 col-residues (l15), once per block
#pragma unroll
    for (int p = 0; p < 8; ++p) {
        float lv1 = v1[p], lv2 = v2[p], lmn = mnn[p], lkv = kvv[p];
        int li1 = i1a[p], li2 = i2a[p], lki = kia[p];
        for (int m = 1; m <= 8; m <<= 1) {
            float o1 = __shfl_xor(lv1, m); int oi1 = __shfl_xor(li1, m);
            float o2 = __shfl_xor(lv2, m); int oi2 = __shfl_xor(li2, m);
            merge_top2(lv1, li1, lv2, li2, o1, oi1, o2, oi2);
            lmn = fminf(lmn, __shfl_xor(lmn, m));
            float ok = __shfl_xor(lkv, m); int oki = __shfl_xor(lki, m);
            bool ck = ok > lkv;
            lkv = ck ? ok : lkv; lki = ck ? oki : lki;
        }
        if (l15 == 0) {
            int rowg = i0 + w * 32 + (p >> 2) * 16 + q * 4 + (p & 3);
            size_t idx = (size_t)rowg * NCH + bx;
            pV1[idx] = lv1; pI1[idx] = li1; pV2[idx] = lv2; pI2[idx] = li2;
            pMn[idx] = lmn; pKv[idx] = lkv; pKi[idx] = lki;
        }
    }
}

// ---------------- K5: merge chunk partials, decode, norms + alpha dots (fused) ----------------
// one wave per row; grid NR/4 x 256 threads
__global__ __launch_bounds__(256) void k_merge_alpha(const float* __restrict__ pV1, const int* __restrict__ pI1,
                                                     const float* __restrict__ pV2, const int* __restrict__ pI2,
                                                     const float* __restrict__ pMn,
                                                     const float* __restrict__ pKv, const int* __restrict__ pKi,
                                                     const int* __restrict__ label, const int* __restrict__ cnt,
                                                     const float* __restrict__ clot,
                                                     float* __restrict__ ap1, float* __restrict__ ap2,
                                                     float* __restrict__ an,
                                                     float* __restrict__ alpha1, float* __restrict__ alpha2) {
    int wid = threadIdx.x >> 6, lane = threadIdx.x & 63;
    int row = blockIdx.x * 4 + wid;
    float v1 = NEGI, v2 = NEGI, mn = POSI, kv = NEGI;
    int i1 = 0, i2 = 0, ki = 0;
    if (lane < NCH) {
        size_t id = (size_t)row * NCH + lane;
        v1 = pV1[id]; i1 = pI1[id]; v2 = pV2[id]; i2 = pI2[id];
        mn = pMn[id]; kv = pKv[id]; ki = pKi[id];
    }
    for (int m = 1; m <= 8; m <<= 1) {   // xor<16 stays within the 16-lane group
        float o1 = __shfl_xor(v1, m); int oi1 = __shfl_xor(i1, m);
        float o2 = __shfl_xor(v2, m); int oi2 = __shfl_xor(i2, m);
        merge_top2(v1, i1, v2, i2, o1, oi1, o2, oi2);
        mn = fminf(mn, __shfl_xor(mn, m));
        float ok = __shfl_xor(kv, m); int oki = __shfl_xor(ki, m);
        bool ck = ok > kv;
        kv = ck ? ok : kv; ki = ck ? oki : ki;
    }
    v1 = __shfl(v1, 0); i1 = __shfl(i1, 0);
    v2 = __shfl(v2, 0); i2 = __shfl(i2, 0);
    mn = __shfl(mn, 0); kv = __shfl(kv, 0); ki = __shfl(ki, 0);

    int cc = cnt[label[row]];
    float a1 = sqrtf(v1);
    int j1 = i1;
    float a2v; int j2;
    if (cc >= 2) {
        a2v = sqrtf(v2);
        j2 = i2;
    } else {
        // single-member class: ref's top-2 falls back to best (max-dist) negative - BIG
        a2v = sqrtf(kv) - BIGF;
        j2 = ki;
    }

    // alpha dots + norms: cos(row, j1), cos(row, j2)
    const float4* c4 = (const float4*)clot;
    float s1 = 0.f, s2 = 0.f, n0 = 0.f, n1 = 0.f, n2 = 0.f;
    for (int t = lane; t < DC / 4; t += 64) {
        float4 a = c4[(size_t)row * (DC / 4) + t];
        float4 b1 = c4[(size_t)j1 * (DC / 4) + t];
        float4 b2 = c4[(size_t)j2 * (DC / 4) + t];
        s1 += a.x * b1.x + a.y * b1.y + a.z * b1.z + a.w * b1.w;
        s2 += a.x * b2.x + a.y * b2.y + a.z * b2.z + a.w * b2.w;
        n0 += a.x * a.x + a.y * a.y + a.z * a.z + a.w * a.w;
        n1 += b1.x * b1.x + b1.y * b1.y + b1.z * b1.z + b1.w * b1.w;
        n2 += b2.x * b2.x + b2.y * b2.y + b2.z * b2.z + b2.w * b2.w;
    }
    for (int m = 1; m < 64; m <<= 1) {
        s1 += __shfl_xor(s1, m); s2 += __shfl_xor(s2, m);
        n0 += __shfl_xor(n0, m); n1 += __shfl_xor(n1, m); n2 += __shfl_xor(n2, m);
    }
    if (lane == 0) {
        ap1[row] = a1; ap2[row] = a2v; an[row] = sqrtf(mn);
        alpha1[row] = s1 / (sqrtf(n0) * sqrtf(n1));
        alpha2[row] = s2 / (sqrtf(n0) * sqrtf(n2));
    }
}

// ---------------- K7: final loss + prec ----------------
__global__ __launch_bounds__(256) void k_final(const float* __restrict__ ap1, const float* __restrict__ ap2,
                                               const float* __restrict__ an,
                                               const float* __restrict__ alpha1, const float* __restrict__ alpha2,
                                               float* __restrict__ out) {
    int tid = threadIdx.x;
    float sl11 = 0.f, sl13 = 0.f, sp = 0.f;
    for (int row = tid; row < NR; row += 256) {
        float a1 = alpha1[row], a2 = alpha2[row];
        float dap1 = ap1[row], dap2 = ap2[row], dan = an[row];
        float y = (a1 < a2) ? -1.f : 1.f;
        float ym = (a1 == a2) ? 0.f : 1.f;
        float x1 = dap2 * ym;
        float x2 = dap1 * ym + MARG * (a1 - a2 - y);
        sl11 += fmaxf(0.f, -y * (x1 - x2) + MARG);
        float ap1m = dap1 + MARG * (a1 - 1.f);
        sl13 += fmaxf(0.f, -(dan - ap1m) + MARG);
        sp += (dan > ap1m) ? 1.f : 0.f;
    }
    for (int m = 1; m < 64; m <<= 1) {
        sl11 += __shfl_xor(sl11, m);
        sl13 += __shfl_xor(sl13, m);
        sp += __shfl_xor(sp, m);
    }
    __shared__ float r11[4], r13[4], rp[4];
    if ((tid & 63) == 0) { r11[tid >> 6] = sl11; r13[tid >> 6] = sl13; rp[tid >> 6] = sp; }
    __syncthreads();
    if (tid == 0) {
        float t11 = r11[0] + r11[1] + r11[2] + r11[3];
        float t13 = r13[0] + r13[1] + r13[2] + r13[3];
        float tp = rp[0] + rp[1] + rp[2] + rp[3];
        out[0] = 0.1f * (t11 / (float)NR) + t13 / (float)NR;
        out[1] = tp / (float)NR;
    }
}

extern "C" void kernel_launch(void* const* d_in, const int* in_sizes, int n_in,
                              void* d_out, int out_size, void* d_ws, size_t ws_size,
                              hipStream_t stream) {
    const float* emb = (const float*)d_in[0];
    const int* label = (const int*)d_in[1];
    const float* clot = (const float*)d_in[2];
    float* out = (float*)d_out;

    char* ws = (char*)d_ws;
    size_t off = 0;
    auto alloc = [&](size_t bytes) -> char* {
        char* p = ws + off;
        off = (off + bytes + 255) & ~(size_t)255;
        return p;
    };
    short* embb = (short*)alloc((size_t)NR * DE * 2);
    float* sq   = (float*)alloc(NR * 4);
    int*   cnt  = (int*)alloc(512 * 4);
    float* pV1  = (float*)alloc((size_t)NR * NCH * 4);
    int*   pI1  = (int*)alloc((size_t)NR * NCH * 4);
    float* pV2  = (float*)alloc((size_t)NR * NCH * 4);
    int*   pI2  = (int*)alloc((size_t)NR * NCH * 4);
    float* pMn  = (float*)alloc((size_t)NR * NCH * 4);
    float* pKv  = (float*)alloc((size_t)NR * NCH * 4);
    int*   pKi  = (int*)alloc((size_t)NR * NCH * 4);
    float* ap1  = (float*)alloc(NR * 4);
    float* ap2  = (float*)alloc(NR * 4);
    float* an   = (float*)alloc(NR * 4);
    float* al1  = (float*)alloc(NR * 4);
    float* al2  = (float*)alloc(NR * 4);

    k_prep_emb<<<dim3(NR), dim3(256), 0, stream>>>(emb, embb, sq);
    k_hist<<<dim3(1), dim3(512), 0, stream>>>(label, cnt);
    k_main<<<dim3(NCH, NR / 128), dim3(256), 0, stream>>>(embb, sq, label,
                                                          pV1, pI1, pV2, pI2, pMn, pKv, pKi);
    k_merge_alpha<<<dim3(NR / 4), dim3(256), 0, stream>>>(pV1, pI1, pV2, pI2, pMn, pKv, pKi,
                                                          label, cnt, clot,
                                                          ap1, ap2, an, al1, al2);
    k_final<<<dim3(1), dim3(256), 0, stream>>>(ap1, ap2, an, al1, al2, out);
}